// Round 1
// baseline (441.460 us; speedup 1.0000x reference)
//
#include <hip/hip_runtime.h>
#include <hip/hip_bf16.h>

// Problem constants (from reference)
#define B      4
#define SEQ    4096
#define DM     1024
#define DK     64

typedef __bf16 bf16x8 __attribute__((ext_vector_type(8)));
typedef float  f32x4  __attribute__((ext_vector_type(4)));

// LDS row stride (elements) for 64-wide bf16 tiles: 72*2B = 144B = 9*16B,
// breaks the 16-way bank conflict of stride-128B ds_read_b128 while keeping
// 16B alignment for b128 accesses.
#define KSTR 72

// ---------------------------------------------------------------------------
// Kernel 1: fused projections. q = X@Wq etc. fp32 accumulate, bf16 output.
// q,k stored [B,S,64] row-major; v stored transposed [B,64,S] so the flash
// kernel's V B-fragments are contiguous ds_read_b128.
// grid: (16384/16, 3), block 256.
// ---------------------------------------------------------------------------
__global__ __launch_bounds__(256) void proj_kernel(
    const float* __restrict__ q_in, const float* __restrict__ k_in,
    const float* __restrict__ v_in,
    const float* __restrict__ Wq, const float* __restrict__ Wk,
    const float* __restrict__ Wv,
    __bf16* __restrict__ qb, __bf16* __restrict__ kb,
    __bf16* __restrict__ vtb)
{
    const int m = blockIdx.y;                    // 0=q, 1=k, 2=v
    const float* in = (m == 0) ? q_in : (m == 1) ? k_in : v_in;
    const float* W  = (m == 0) ? Wq   : (m == 1) ? Wk   : Wv;

    const int rowbase = blockIdx.x * 16;         // row tile over B*S = 16384
    const int tid = threadIdx.x;
    const int c  = tid & 63;                     // output column 0..63
    const int rq = tid >> 6;                     // wave id: rows rq*4 .. rq*4+3

    __shared__ float in_s[16][128];              // input row chunk (fp32)
    __shared__ float W_s[128 * 64];              // W chunk (fp32)
    __shared__ __bf16 vs[16][66];                // v-tile transpose staging (+2 pad)

    float acc[4] = {0.f, 0.f, 0.f, 0.f};

    for (int kc = 0; kc < DM; kc += 128) {
        __syncthreads();
        // stage 16 input rows x 128 cols: thread t -> row t>>4, 8 floats
        {
            const float* src = in + (size_t)(rowbase + (tid >> 4)) * DM + kc + (tid & 15) * 8;
            float4 a0 = *(const float4*)src;
            float4 a1 = *(const float4*)(src + 4);
            *(float4*)&in_s[tid >> 4][(tid & 15) * 8]     = a0;
            *(float4*)&in_s[tid >> 4][(tid & 15) * 8 + 4] = a1;
        }
        // stage W chunk [128][64] fp32 = 8192 floats
        {
            const float* wsrc = W + (size_t)kc * DK;
            #pragma unroll
            for (int i = 0; i < 8; ++i) {
                int flat = i * 1024 + tid * 4;
                *(float4*)&W_s[flat] = *(const float4*)(wsrc + flat);
            }
        }
        __syncthreads();

        #pragma unroll 4
        for (int k = 0; k < 128; ++k) {
            float wv = W_s[k * 64 + c];          // 64 consecutive lanes -> 2-way bank (free)
            #pragma unroll
            for (int i = 0; i < 4; ++i)
                acc[i] += in_s[rq * 4 + i][k] * wv;   // wave-uniform -> broadcast
        }
    }

    if (m < 2) {
        __bf16* outb = (m == 0) ? qb : kb;
        #pragma unroll
        for (int i = 0; i < 4; ++i)
            outb[(size_t)(rowbase + rq * 4 + i) * DK + c] = (__bf16)acc[i];
    } else {
        // transpose 16x64 tile through LDS, write vtb[B][64][S] coalesced-ish
        __syncthreads();
        #pragma unroll
        for (int i = 0; i < 4; ++i)
            vs[rq * 4 + i][c] = (__bf16)acc[i];
        __syncthreads();
        const int c2 = tid >> 2;                 // dk column 0..63
        const int x  = tid & 3;
        const int bb = rowbase >> 12;            // batch (4096 rows per batch, tile-aligned)
        const int s0 = rowbase & (SEQ - 1);
        #pragma unroll
        for (int y = 0; y < 4; ++y)
            vtb[(size_t)(bb * DK + c2) * SEQ + s0 + x * 4 + y] = vs[x * 4 + y][c2];
    }
}

// ---------------------------------------------------------------------------
// Kernel 2: causal flash attention, bf16 MFMA 16x16x32, fp32 accumulate.
// grid: (S/64, B), block 256 (4 waves). Wave w handles q rows [qt*64+w*16, +16).
// K-tile = 64 key positions per iteration.
// ---------------------------------------------------------------------------
__global__ __launch_bounds__(256) void flash_kernel(
    const __bf16* __restrict__ qb, const __bf16* __restrict__ kb,
    const __bf16* __restrict__ vtb, float* __restrict__ out)
{
    const int qt  = blockIdx.x;                  // q tile 0..63
    const int bb  = blockIdx.y;                  // batch
    const int tid = threadIdx.x;
    const int w    = tid >> 6;                   // wave 0..3
    const int lane = tid & 63;
    const int quad = lane >> 4;                  // 0..3
    const int l15  = lane & 15;

    __shared__ __bf16 Ks[64 * KSTR];             // [kpos][dk], padded
    __shared__ __bf16 Vs[64 * KSTR];             // [dk][kpos] (V^T), padded
    __shared__ __bf16 Ps[4][16 * KSTR];          // per-wave P round-trip

    const int qrow_base = qt * 64 + w * 16;

    // Q A-fragments (held in registers for the whole kernel)
    bf16x8 qf[2];
    {
        const __bf16* qp = qb + ((size_t)(bb * SEQ + qrow_base + l15)) * DK + quad * 8;
        qf[0] = *(const bf16x8*)(qp);
        qf[1] = *(const bf16x8*)(qp + 32);
    }

    f32x4 of[4];
    #pragma unroll
    for (int nf = 0; nf < 4; ++nf) of[nf] = (f32x4){0.f, 0.f, 0.f, 0.f};
    float m_r[4], l_r[4];
    #pragma unroll
    for (int r = 0; r < 4; ++r) { m_r[r] = -3.0e38f; l_r[r] = 0.f; }

    const float SC = 0.125f * 1.44269504088896340736f;   // 1/sqrt(64) * log2(e)

    for (int kt = 0; kt <= qt; ++kt) {
        __syncthreads();   // protect Ks/Vs from previous iteration's readers
        {
            const int r  = tid >> 2;             // 0..63
            const int cc = (tid & 3) * 16;       // 0,16,32,48
            const __bf16* kg = kb + ((size_t)(bb * SEQ + kt * 64 + r)) * DK + cc;
            *(bf16x8*)(&Ks[r * KSTR + cc])     = *(const bf16x8*)(kg);
            *(bf16x8*)(&Ks[r * KSTR + cc + 8]) = *(const bf16x8*)(kg + 8);
            const __bf16* vg = vtb + ((size_t)(bb * DK + r)) * SEQ + kt * 64 + cc;
            *(bf16x8*)(&Vs[r * KSTR + cc])     = *(const bf16x8*)(vg);
            *(bf16x8*)(&Vs[r * KSTR + cc + 8]) = *(const bf16x8*)(vg + 8);
        }
        __syncthreads();

        // ---- S = Q K^T (16 rows x 64 cols per wave) ----
        f32x4 sf[4];
        #pragma unroll
        for (int nf = 0; nf < 4; ++nf) {
            sf[nf] = (f32x4){0.f, 0.f, 0.f, 0.f};
            #pragma unroll
            for (int ch = 0; ch < 2; ++ch) {
                bf16x8 kf = *(const bf16x8*)(&Ks[(nf * 16 + l15) * KSTR + ch * 32 + quad * 8]);
                sf[nf] = __builtin_amdgcn_mfma_f32_16x16x32_bf16(qf[ch], kf, sf[nf], 0, 0, 0);
            }
        }

        // ---- scale + causal mask + row max ----
        const bool diag = (kt == qt);
        float rowmax[4] = {-3.0e38f, -3.0e38f, -3.0e38f, -3.0e38f};
        #pragma unroll
        for (int nf = 0; nf < 4; ++nf) {
            #pragma unroll
            for (int r = 0; r < 4; ++r) {
                float s = sf[nf][r] * SC;
                if (diag) {
                    const int kcol = nf * 16 + l15;
                    const int qrow = w * 16 + quad * 4 + r;
                    if (kcol > qrow) s = -3.0e38f;
                }
                sf[nf][r] = s;
                rowmax[r] = fmaxf(rowmax[r], s);
            }
        }
        #pragma unroll
        for (int r = 0; r < 4; ++r) {
            float v = rowmax[r];
            v = fmaxf(v, __shfl_xor(v, 1));
            v = fmaxf(v, __shfl_xor(v, 2));
            v = fmaxf(v, __shfl_xor(v, 4));
            v = fmaxf(v, __shfl_xor(v, 8));
            rowmax[r] = v;
        }

        // ---- online softmax update ----
        float alpha[4], rs[4];
        #pragma unroll
        for (int r = 0; r < 4; ++r) {
            const float nm = fmaxf(m_r[r], rowmax[r]);
            alpha[r] = __builtin_amdgcn_exp2f(m_r[r] - nm);
            m_r[r] = nm;
            rs[r] = 0.f;
        }
        #pragma unroll
        for (int nf = 0; nf < 4; ++nf) {
            #pragma unroll
            for (int r = 0; r < 4; ++r) {
                const float p = __builtin_amdgcn_exp2f(sf[nf][r] - m_r[r]);
                rs[r] += p;
                Ps[w][(quad * 4 + r) * KSTR + nf * 16 + l15] = (__bf16)p;
            }
        }
        #pragma unroll
        for (int r = 0; r < 4; ++r) {
            float v = rs[r];
            v += __shfl_xor(v, 1);
            v += __shfl_xor(v, 2);
            v += __shfl_xor(v, 4);
            v += __shfl_xor(v, 8);
            l_r[r] = l_r[r] * alpha[r] + v;
        }
        #pragma unroll
        for (int nf = 0; nf < 4; ++nf)
            #pragma unroll
            for (int r = 0; r < 4; ++r)
                of[nf][r] *= alpha[r];

        // ---- O += P V  (P via LDS round-trip into A-layout) ----
        bf16x8 pf[2];
        pf[0] = *(const bf16x8*)(&Ps[w][l15 * KSTR + quad * 8]);
        pf[1] = *(const bf16x8*)(&Ps[w][l15 * KSTR + 32 + quad * 8]);
        #pragma unroll
        for (int nf = 0; nf < 4; ++nf) {
            #pragma unroll
            for (int ch = 0; ch < 2; ++ch) {
                bf16x8 vf = *(const bf16x8*)(&Vs[(nf * 16 + l15) * KSTR + ch * 32 + quad * 8]);
                of[nf] = __builtin_amdgcn_mfma_f32_16x16x32_bf16(pf[ch], vf, of[nf], 0, 0, 0);
            }
        }
    }

    // ---- epilogue: O / l ----
    float inv_l[4];
    #pragma unroll
    for (int r = 0; r < 4; ++r) inv_l[r] = 1.0f / l_r[r];
    #pragma unroll
    for (int nf = 0; nf < 4; ++nf)
        #pragma unroll
        for (int r = 0; r < 4; ++r)
            out[(size_t)(bb * SEQ + qrow_base + quad * 4 + r) * DK + nf * 16 + l15] =
                of[nf][r] * inv_l[r];
}

// ---------------------------------------------------------------------------
extern "C" void kernel_launch(void* const* d_in, const int* in_sizes, int n_in,
                              void* d_out, int out_size, void* d_ws, size_t ws_size,
                              hipStream_t stream)
{
    const float* queries = (const float*)d_in[0];
    const float* keys    = (const float*)d_in[1];
    const float* values  = (const float*)d_in[2];
    // d_in[3] = mask (unused; causality is implicit)
    const float* Wq = (const float*)d_in[4];
    const float* Wk = (const float*)d_in[5];
    const float* Wv = (const float*)d_in[6];
    float* out = (float*)d_out;

    // workspace: q [B,S,64] bf16, k [B,S,64] bf16, v^T [B,64,S] bf16
    __bf16* qb  = (__bf16*)d_ws;
    __bf16* kb  = qb + (size_t)B * SEQ * DK;
    __bf16* vtb = kb + (size_t)B * SEQ * DK;

    dim3 pgrid((B * SEQ) / 16, 3);
    proj_kernel<<<pgrid, 256, 0, stream>>>(queries, keys, values, Wq, Wk, Wv,
                                           qb, kb, vtb);

    dim3 fgrid(SEQ / 64, B);
    flash_kernel<<<fgrid, 256, 0, stream>>>(qb, kb, vtb, out);
}

// Round 2
// 299.863 us; speedup vs baseline: 1.4722x; 1.4722x over previous
//
#include <hip/hip_runtime.h>
#include <hip/hip_bf16.h>

// Problem constants (from reference)
#define B      4
#define SEQ    4096
#define DM     1024
#define DK     64
#define NSPLIT 4      // flash-decoding KV splits per q-tile

typedef __bf16 bf16x8 __attribute__((ext_vector_type(8)));
typedef __bf16 bf16x4 __attribute__((ext_vector_type(4)));
typedef float  f32x4  __attribute__((ext_vector_type(4)));

// LDS row stride (elements) for 64-wide bf16 tiles: 72*2B = 144B = 9*16B,
// breaks the 16-way bank conflict of stride-128B ds_read_b128 while keeping
// 16B alignment for b128 accesses.
#define KSTR 72

// ---------------------------------------------------------------------------
// Kernel 0: W [1024][64] fp32  ->  Wt [3][64][1024] bf16 (transposed).
// grid (16, 3), block 256. Tile transpose through LDS.
// ---------------------------------------------------------------------------
__global__ __launch_bounds__(256) void wt_kernel(
    const float* __restrict__ Wq, const float* __restrict__ Wk,
    const float* __restrict__ Wv, __bf16* __restrict__ Wt)
{
    const int mat = blockIdx.y;
    const float* W = (mat == 0) ? Wq : (mat == 1) ? Wk : Wv;
    const int k0 = blockIdx.x * 64;
    const int tid = threadIdx.x;

    __shared__ float t[64][65];

    const int r = tid >> 2;             // 0..63 (k within tile)
    const int c = (tid & 3) * 16;       // 0,16,32,48 (n)
    {
        const float* src = W + (size_t)(k0 + r) * DK + c;
        #pragma unroll
        for (int j = 0; j < 4; ++j) {
            float4 a = *(const float4*)(src + j * 4);
            t[r][c + j * 4 + 0] = a.x; t[r][c + j * 4 + 1] = a.y;
            t[r][c + j * 4 + 2] = a.z; t[r][c + j * 4 + 3] = a.w;
        }
    }
    __syncthreads();
    // write side: n = tid>>2, k chunk = (tid&3)*16
    const int n  = tid >> 2;
    const int kk = (tid & 3) * 16;
    bf16x8 b0, b1;
    #pragma unroll
    for (int j = 0; j < 8; ++j) b0[j] = (__bf16)t[kk + j][n];
    #pragma unroll
    for (int j = 0; j < 8; ++j) b1[j] = (__bf16)t[kk + 8 + j][n];
    __bf16* dst = Wt + (size_t)(mat * DK + n) * DM + k0 + kk;
    *(bf16x8*)(dst)     = b0;
    *(bf16x8*)(dst + 8) = b1;
}

// ---------------------------------------------------------------------------
// Kernel 1: MFMA projections. q = X@Wq etc. bf16 MFMA, fp32 accumulate.
// q,k stored [B,S,64]; v stored transposed [B,64,S].
// grid: (B*S/64, 3), block 256 (4 waves; wave w -> rows w*16..w*16+15).
// ---------------------------------------------------------------------------
__global__ __launch_bounds__(256) void proj_mfma_kernel(
    const float* __restrict__ q_in, const float* __restrict__ k_in,
    const float* __restrict__ v_in, const __bf16* __restrict__ Wt,
    __bf16* __restrict__ qb, __bf16* __restrict__ kb,
    __bf16* __restrict__ vtb)
{
    const int m = blockIdx.y;                    // 0=q, 1=k, 2=v
    const float* in = (m == 0) ? q_in : (m == 1) ? k_in : v_in;
    const __bf16* wt = Wt + (size_t)m * DK * DM; // [64][1024] bf16

    const int rowbase = blockIdx.x * 64;
    const int tid  = threadIdx.x;
    const int w    = tid >> 6;
    const int lane = tid & 63;
    const int quad = lane >> 4;
    const int l15  = lane & 15;

    __shared__ __bf16 As[64 * KSTR];
    __shared__ __bf16 Ws[64 * KSTR];

    f32x4 acc[4];
    #pragma unroll
    for (int nf = 0; nf < 4; ++nf) acc[nf] = (f32x4){0.f, 0.f, 0.f, 0.f};

    const int ar = tid >> 2;             // staging row 0..63
    const int ac = (tid & 3) * 16;       // staging col chunk

    for (int kc = 0; kc < DM; kc += 64) {
        __syncthreads();
        // stage A 64x64 fp32 -> bf16 LDS
        {
            const float* ap = in + (size_t)(rowbase + ar) * DM + kc + ac;
            float4 f0 = *(const float4*)(ap);
            float4 f1 = *(const float4*)(ap + 4);
            float4 f2 = *(const float4*)(ap + 8);
            float4 f3 = *(const float4*)(ap + 12);
            bf16x8 b0, b1;
            b0[0]=(__bf16)f0.x; b0[1]=(__bf16)f0.y; b0[2]=(__bf16)f0.z; b0[3]=(__bf16)f0.w;
            b0[4]=(__bf16)f1.x; b0[5]=(__bf16)f1.y; b0[6]=(__bf16)f1.z; b0[7]=(__bf16)f1.w;
            b1[0]=(__bf16)f2.x; b1[1]=(__bf16)f2.y; b1[2]=(__bf16)f2.z; b1[3]=(__bf16)f2.w;
            b1[4]=(__bf16)f3.x; b1[5]=(__bf16)f3.y; b1[6]=(__bf16)f3.z; b1[7]=(__bf16)f3.w;
            *(bf16x8*)&As[ar * KSTR + ac]     = b0;
            *(bf16x8*)&As[ar * KSTR + ac + 8] = b1;
        }
        // stage Wt 64x64 bf16 (already transposed: [n][k])
        {
            const __bf16* wp = wt + (size_t)ar * DM + kc + ac;
            *(bf16x8*)&Ws[ar * KSTR + ac]     = *(const bf16x8*)(wp);
            *(bf16x8*)&Ws[ar * KSTR + ac + 8] = *(const bf16x8*)(wp + 8);
        }
        __syncthreads();

        bf16x8 af0 = *(const bf16x8*)&As[(w * 16 + l15) * KSTR + quad * 8];
        bf16x8 af1 = *(const bf16x8*)&As[(w * 16 + l15) * KSTR + 32 + quad * 8];
        #pragma unroll
        for (int nf = 0; nf < 4; ++nf) {
            bf16x8 w0 = *(const bf16x8*)&Ws[(nf * 16 + l15) * KSTR + quad * 8];
            bf16x8 w1 = *(const bf16x8*)&Ws[(nf * 16 + l15) * KSTR + 32 + quad * 8];
            acc[nf] = __builtin_amdgcn_mfma_f32_16x16x32_bf16(af0, w0, acc[nf], 0, 0, 0);
            acc[nf] = __builtin_amdgcn_mfma_f32_16x16x32_bf16(af1, w1, acc[nf], 0, 0, 0);
        }
    }

    // epilogue: C-layout col = l15 (within nf tile), row = quad*4+r (within wave tile)
    if (m < 2) {
        __bf16* outb = (m == 0) ? qb : kb;
        #pragma unroll
        for (int nf = 0; nf < 4; ++nf)
            #pragma unroll
            for (int r = 0; r < 4; ++r)
                outb[(size_t)(rowbase + w * 16 + quad * 4 + r) * DK + nf * 16 + l15] =
                    (__bf16)acc[nf][r];
    } else {
        const int bb = rowbase >> 12;
        const int s0 = (rowbase & (SEQ - 1)) + w * 16 + quad * 4;
        #pragma unroll
        for (int nf = 0; nf < 4; ++nf) {
            bf16x4 v4;
            #pragma unroll
            for (int r = 0; r < 4; ++r) v4[r] = (__bf16)acc[nf][r];
            *(bf16x4*)&vtb[(size_t)(bb * DK + nf * 16 + l15) * SEQ + s0] = v4;
        }
    }
}

// ---------------------------------------------------------------------------
// Kernel 2: causal flash attention with KV-split. bf16 MFMA 16x16x32.
// grid: (S/64, B, NSPLIT), block 256 (4 waves). Wave w: q rows qt*64+w*16..+16.
// Split z handles k-tiles [niters*z/4, niters*(z+1)/4). Writes unnormalized
// partial O + (m, l) per row.
// ---------------------------------------------------------------------------
__global__ __launch_bounds__(256) void flash_kernel(
    const __bf16* __restrict__ qb, const __bf16* __restrict__ kb,
    const __bf16* __restrict__ vtb, float* __restrict__ Opart,
    float* __restrict__ mpart, float* __restrict__ lpart)
{
    const int qt  = blockIdx.x;                  // q tile 0..63
    const int bb  = blockIdx.y;                  // batch
    const int z   = blockIdx.z;                  // split
    const int tid = threadIdx.x;
    const int w    = tid >> 6;
    const int lane = tid & 63;
    const int quad = lane >> 4;
    const int l15  = lane & 15;

    __shared__ __bf16 Ks[64 * KSTR];
    __shared__ __bf16 Vs[64 * KSTR];
    __shared__ __bf16 Ps[4][16 * KSTR];

    const int qrow_base = qt * 64 + w * 16;
    const int niters = qt + 1;
    const int kt0 = (niters * z) / NSPLIT;
    const int kt1 = (niters * (z + 1)) / NSPLIT;

    bf16x8 qf[2];
    {
        const __bf16* qp = qb + ((size_t)(bb * SEQ + qrow_base + l15)) * DK + quad * 8;
        qf[0] = *(const bf16x8*)(qp);
        qf[1] = *(const bf16x8*)(qp + 32);
    }

    f32x4 of[4];
    #pragma unroll
    for (int nf = 0; nf < 4; ++nf) of[nf] = (f32x4){0.f, 0.f, 0.f, 0.f};
    float m_r[4], l_r[4];
    #pragma unroll
    for (int r = 0; r < 4; ++r) { m_r[r] = -3.0e38f; l_r[r] = 0.f; }

    const float SC = 0.125f * 1.44269504088896340736f;   // 1/sqrt(64) * log2(e)

    for (int kt = kt0; kt < kt1; ++kt) {
        __syncthreads();
        {
            const int r  = tid >> 2;
            const int cc = (tid & 3) * 16;
            const __bf16* kg = kb + ((size_t)(bb * SEQ + kt * 64 + r)) * DK + cc;
            *(bf16x8*)(&Ks[r * KSTR + cc])     = *(const bf16x8*)(kg);
            *(bf16x8*)(&Ks[r * KSTR + cc + 8]) = *(const bf16x8*)(kg + 8);
            const __bf16* vg = vtb + ((size_t)(bb * DK + r)) * SEQ + kt * 64 + cc;
            *(bf16x8*)(&Vs[r * KSTR + cc])     = *(const bf16x8*)(vg);
            *(bf16x8*)(&Vs[r * KSTR + cc + 8]) = *(const bf16x8*)(vg + 8);
        }
        __syncthreads();

        // ---- S = Q K^T ----
        f32x4 sf[4];
        #pragma unroll
        for (int nf = 0; nf < 4; ++nf) {
            sf[nf] = (f32x4){0.f, 0.f, 0.f, 0.f};
            #pragma unroll
            for (int ch = 0; ch < 2; ++ch) {
                bf16x8 kf = *(const bf16x8*)(&Ks[(nf * 16 + l15) * KSTR + ch * 32 + quad * 8]);
                sf[nf] = __builtin_amdgcn_mfma_f32_16x16x32_bf16(qf[ch], kf, sf[nf], 0, 0, 0);
            }
        }

        // ---- scale + causal mask + row max ----
        const bool diag = (kt == qt);
        float rowmax[4] = {-3.0e38f, -3.0e38f, -3.0e38f, -3.0e38f};
        #pragma unroll
        for (int nf = 0; nf < 4; ++nf) {
            #pragma unroll
            for (int r = 0; r < 4; ++r) {
                float s = sf[nf][r] * SC;
                if (diag) {
                    const int kcol = nf * 16 + l15;
                    const int qrow = w * 16 + quad * 4 + r;
                    if (kcol > qrow) s = -3.0e38f;
                }
                sf[nf][r] = s;
                rowmax[r] = fmaxf(rowmax[r], s);
            }
        }
        #pragma unroll
        for (int r = 0; r < 4; ++r) {
            float v = rowmax[r];
            v = fmaxf(v, __shfl_xor(v, 1));
            v = fmaxf(v, __shfl_xor(v, 2));
            v = fmaxf(v, __shfl_xor(v, 4));
            v = fmaxf(v, __shfl_xor(v, 8));
            rowmax[r] = v;
        }

        // ---- online softmax update ----
        float alpha[4], rs[4];
        #pragma unroll
        for (int r = 0; r < 4; ++r) {
            const float nm = fmaxf(m_r[r], rowmax[r]);
            alpha[r] = __builtin_amdgcn_exp2f(m_r[r] - nm);
            m_r[r] = nm;
            rs[r] = 0.f;
        }
        #pragma unroll
        for (int nf = 0; nf < 4; ++nf) {
            #pragma unroll
            for (int r = 0; r < 4; ++r) {
                const float p = __builtin_amdgcn_exp2f(sf[nf][r] - m_r[r]);
                rs[r] += p;
                Ps[w][(quad * 4 + r) * KSTR + nf * 16 + l15] = (__bf16)p;
            }
        }
        #pragma unroll
        for (int r = 0; r < 4; ++r) {
            float v = rs[r];
            v += __shfl_xor(v, 1);
            v += __shfl_xor(v, 2);
            v += __shfl_xor(v, 4);
            v += __shfl_xor(v, 8);
            l_r[r] = l_r[r] * alpha[r] + v;
        }
        #pragma unroll
        for (int nf = 0; nf < 4; ++nf)
            #pragma unroll
            for (int r = 0; r < 4; ++r)
                of[nf][r] *= alpha[r];

        // ---- O += P V ----
        bf16x8 pf[2];
        pf[0] = *(const bf16x8*)(&Ps[w][l15 * KSTR + quad * 8]);
        pf[1] = *(const bf16x8*)(&Ps[w][l15 * KSTR + 32 + quad * 8]);
        #pragma unroll
        for (int nf = 0; nf < 4; ++nf) {
            #pragma unroll
            for (int ch = 0; ch < 2; ++ch) {
                bf16x8 vf = *(const bf16x8*)(&Vs[(nf * 16 + l15) * KSTR + ch * 32 + quad * 8]);
                of[nf] = __builtin_amdgcn_mfma_f32_16x16x32_bf16(pf[ch], vf, of[nf], 0, 0, 0);
            }
        }
    }

    // ---- epilogue: write unnormalized partials ----
    float* Op = Opart + ((size_t)(z * B + bb) * SEQ + qrow_base) * DK;
    #pragma unroll
    for (int nf = 0; nf < 4; ++nf)
        #pragma unroll
        for (int r = 0; r < 4; ++r)
            Op[(size_t)(quad * 4 + r) * DK + nf * 16 + l15] = of[nf][r];
    if (l15 == 0) {
        const size_t base = (size_t)(z * B + bb) * SEQ + qrow_base + quad * 4;
        #pragma unroll
        for (int r = 0; r < 4; ++r) {
            mpart[base + r] = m_r[r];
            lpart[base + r] = l_r[r];
        }
    }
}

// ---------------------------------------------------------------------------
// Kernel 3: combine partials. out = sum_z O_z e^{m_z-M} / sum_z l_z e^{m_z-M}
// ---------------------------------------------------------------------------
__global__ __launch_bounds__(256) void combine_kernel(
    const float* __restrict__ Opart, const float* __restrict__ mpart,
    const float* __restrict__ lpart, float* __restrict__ out)
{
    const int idx = blockIdx.x * 256 + threadIdx.x;   // 0 .. B*SEQ*DK-1
    const int col = idx & (DK - 1);
    const int row = idx >> 6;                         // b*SEQ + s

    float mv[NSPLIT];
    float M = -3.0e38f;
    #pragma unroll
    for (int z = 0; z < NSPLIT; ++z) {
        mv[z] = mpart[(size_t)z * (B * SEQ) + row];
        M = fmaxf(M, mv[z]);
    }
    float L = 0.f, o = 0.f;
    #pragma unroll
    for (int z = 0; z < NSPLIT; ++z) {
        const float wz = __builtin_amdgcn_exp2f(mv[z] - M);
        L += lpart[(size_t)z * (B * SEQ) + row] * wz;
        o += Opart[((size_t)z * (B * SEQ) + row) * DK + col] * wz;
    }
    out[idx] = o / L;
}

// ---------------------------------------------------------------------------
extern "C" void kernel_launch(void* const* d_in, const int* in_sizes, int n_in,
                              void* d_out, int out_size, void* d_ws, size_t ws_size,
                              hipStream_t stream)
{
    const float* queries = (const float*)d_in[0];
    const float* keys    = (const float*)d_in[1];
    const float* values  = (const float*)d_in[2];
    // d_in[3] = mask (unused; causality is implicit)
    const float* Wq = (const float*)d_in[4];
    const float* Wk = (const float*)d_in[5];
    const float* Wv = (const float*)d_in[6];
    float* out = (float*)d_out;

    // workspace layout
    char* p = (char*)d_ws;
    __bf16* qb  = (__bf16*)p;  p += (size_t)B * SEQ * DK * 2;
    __bf16* kb  = (__bf16*)p;  p += (size_t)B * SEQ * DK * 2;
    __bf16* vtb = (__bf16*)p;  p += (size_t)B * SEQ * DK * 2;
    __bf16* Wt  = (__bf16*)p;  p += (size_t)3 * DK * DM * 2;
    float* Opart = (float*)p;  p += (size_t)NSPLIT * B * SEQ * DK * 4;
    float* mpart = (float*)p;  p += (size_t)NSPLIT * B * SEQ * 4;
    float* lpart = (float*)p;  p += (size_t)NSPLIT * B * SEQ * 4;

    wt_kernel<<<dim3(DM / 64, 3), 256, 0, stream>>>(Wq, Wk, Wv, Wt);

    proj_mfma_kernel<<<dim3((B * SEQ) / 64, 3), 256, 0, stream>>>(
        queries, keys, values, Wt, qb, kb, vtb);

    flash_kernel<<<dim3(SEQ / 64, B, NSPLIT), 256, 0, stream>>>(
        qb, kb, vtb, Opart, mpart, lpart);

    combine_kernel<<<(B * SEQ * DK) / 256, 256, 0, stream>>>(
        Opart, mpart, lpart, out);
}